// Round 17
// baseline (516.619 us; speedup 1.0000x reference)
//
#include <hip/hip_runtime.h>
#include <hip/hip_bf16.h>
#include <stdint.h>

typedef __attribute__((ext_vector_type(8))) short short8;
typedef __attribute__((ext_vector_type(4))) short short4v;
typedef __attribute__((ext_vector_type(2))) short short2v;
typedef __attribute__((ext_vector_type(4))) float floatx4;

__device__ __forceinline__ unsigned short f2b(float f) {
  unsigned u = __builtin_bit_cast(unsigned, f);
  unsigned r = u + 0x7fffu + ((u >> 16) & 1u);
  return (unsigned short)(r >> 16);
}
__device__ __forceinline__ float b2f(unsigned short h) {
  unsigned u = ((unsigned)h) << 16;
  return __builtin_bit_cast(float, u);
}
__device__ __forceinline__ void glds16(const unsigned short* src, unsigned short* dst) {
  __builtin_amdgcn_global_load_lds((const __attribute__((address_space(1))) void*)src,
                                   (__attribute__((address_space(3))) void*)dst, 16, 0, 0);
}
// epilogue LDS swizzle: row r (0..255), o = byte offset in 512B row.
__device__ __forceinline__ int swz(int r, int o) {
  return (r << 9) + (o ^ ((((o >> 7) & 3) ^ (r & 7)) << 4));
}
// T1: bijective XCD-contiguous work remap (requires nwg % 8 == 0).
__device__ __forceinline__ void xcd_remap(int& bx, int& by, int& bz) {
  const int gx = gridDim.x, gy = gridDim.y;
  const int nwg = gx * gy * (int)gridDim.z;
  int lin = bx + gx * (by + gy * bz);
  lin = (lin & 7) * (nwg >> 3) + (lin >> 3);
  bx = lin % gx; const int r = lin / gx;
  by = r % gy; bz = r / gy;
}

// ---------------------------------------------------------------------------
// 256x256-tile TN GEMM core, BK=64 (best measured for streaming GEMMs):
// 512 thr = 8 waves (2Mx4N); 2-buffer ring (2x64KB); per tile: vmcnt(0)
// [full-tile latency cover] -> barrier -> stage(t+1) -> {kk0: read+64 MFMA;
// kk1: read+64 MFMA}. 1 barrier per 64 MFMA.
// EPI 0: staged bf16 C. EPI 1: split-K(16) bf16 partials. EPI 2/3: QKV scatter.
// EPI 4/5: PV tiles -> padded NHWC conv inputs (fused from_patches).
// ---------------------------------------------------------------------------
struct GemmP {
  const unsigned short* A;
  const unsigned short* B;
  long sAb, sBb;
  int lda, ldb, K;
  unsigned short* C; long sCb; int ldc;
  const float* bias;
  unsigned short *Q0, *K0, *V0t, *Q1, *K1, *V1t;
};

template<int EPI>
__global__ __launch_bounds__(512) void gemm256(GemmP p) {
  __shared__ __align__(16) unsigned short LDS[65536];
  const int tid = threadIdx.x;
  const int wv = tid >> 6, lane = tid & 63;
  const int wm = wv >> 2, wn = wv & 3;
  const int g = lane >> 4, l16 = lane & 15;
  int bx = blockIdx.x, by = blockIdx.y, bz = blockIdx.z;
  xcd_remap(bx, by, bz);
  const int m0 = by * 256, n0 = bx * 256;

  int bb = bz, koff = 0, Keff = p.K;
  if constexpr (EPI == 1) { bb = bz >> 4; koff = (bz & 15) * (p.K >> 4); Keff = p.K >> 4; }
  const unsigned short* Ab = p.A + (long)bb * p.sAb + (long)m0 * p.lda + koff;
  const unsigned short* Bb = p.B + (long)bb * p.sBb + (long)n0 * p.ldb + koff;
  const int NT = Keff >> 6;

  const int r0 = tid >> 3;
  const int cs8 = (tid & 7) ^ (r0 & 7);
  const unsigned short* aS[4];
  const unsigned short* bS[4];
#pragma unroll
  for (int i = 0; i < 4; ++i) {
    aS[i] = Ab + (long)(r0 + 64 * i) * p.lda + cs8 * 8;
    bS[i] = Bb + (long)(r0 + 64 * i) * p.ldb + cs8 * 8;
  }
  unsigned short* const lds0 = (unsigned short*)LDS;
  const int wbase = wv * 512;

  auto STAGE = [&](int t) {
    unsigned short* d = lds0 + (t & 1) * 32768;
    const long ko = (long)t * 64;
#pragma unroll
    for (int i = 0; i < 4; ++i) glds16(aS[i] + ko, d + i * 4096 + wbase);
#pragma unroll
    for (int i = 0; i < 4; ++i) glds16(bS[i] + ko, d + 16384 + i * 4096 + wbase);
  };

  STAGE(0);

  floatx4 acc[8][4];
  const floatx4 z4 = {0.f, 0.f, 0.f, 0.f};
#pragma unroll
  for (int i = 0; i < 8; ++i)
#pragma unroll
    for (int j = 0; j < 4; ++j) acc[i][j] = z4;

  const int lmask = l16 & 7;
  const int loff0 = l16 * 64 + ((g ^ lmask) * 8);
  const int aRowB = wm * 128;

  for (int t = 0; t < NT; ++t) {
    const unsigned short* As = lds0 + (t & 1) * 32768;
    const unsigned short* Bs = As + 16384;
    asm volatile("s_waitcnt vmcnt(0)" ::: "memory");
    __builtin_amdgcn_s_barrier();
    __builtin_amdgcn_sched_barrier(0);
    if (t + 1 < NT) STAGE(t + 1);
#pragma unroll
    for (int kk = 0; kk < 2; ++kk) {
      const int lo = loff0 ^ (kk * 32);
      short8 bf[4], af[4], ag[4];
#pragma unroll
      for (int ni = 0; ni < 4; ++ni)
        bf[ni] = *(const short8*)(Bs + (wn * 64 + ni * 16) * 64 + lo);
#pragma unroll
      for (int mi = 0; mi < 4; ++mi)
        af[mi] = *(const short8*)(As + (aRowB + mi * 16) * 64 + lo);
#pragma unroll
      for (int mi = 0; mi < 4; ++mi)
        ag[mi] = *(const short8*)(As + (aRowB + 64 + mi * 16) * 64 + lo);
      __builtin_amdgcn_s_setprio(1);
#pragma unroll
      for (int mi = 0; mi < 4; ++mi)
#pragma unroll
        for (int ni = 0; ni < 4; ++ni)
          acc[mi][ni] = __builtin_amdgcn_mfma_f32_16x16x32_bf16(af[mi], bf[ni], acc[mi][ni], 0, 0, 0);
#pragma unroll
      for (int mi = 0; mi < 4; ++mi)
#pragma unroll
        for (int ni = 0; ni < 4; ++ni)
          acc[4 + mi][ni] = __builtin_amdgcn_mfma_f32_16x16x32_bf16(ag[mi], bf[ni], acc[4 + mi][ni], 0, 0, 0);
      __builtin_amdgcn_s_setprio(0);
    }
  }

  if constexpr (EPI == 1) {          // bf16 partial store
    unsigned short* C = p.C + (long)bz * p.sCb;
#pragma unroll
    for (int mi = 0; mi < 8; ++mi) {
#pragma unroll
      for (int ni = 0; ni < 4; ++ni) {
        const int col = n0 + wn * 64 + ni * 16 + l16;
#pragma unroll
        for (int r4 = 0; r4 < 4; ++r4) {
          const int row = m0 + wm * 128 + mi * 16 + g * 4 + r4;
          C[(long)row * p.ldc + col] = f2b(acc[mi][ni][r4]);
        }
      }
    }
  } else {
    // ------- staged epilogue: acc (+bias/scale for EPI2/3) -> LDS tile -------
    __syncthreads();
    char* shb = (char*)LDS;
    const int sel = (EPI == 2) ? (m0 >> 10) : (m0 >> 8);
#pragma unroll
    for (int mi = 0; mi < 8; ++mi) {
#pragma unroll
      for (int ni = 0; ni < 4; ++ni) {
        const int c = wn * 64 + ni * 16 + l16;
#pragma unroll
        for (int r4 = 0; r4 < 4; ++r4) {
          const int rr = wm * 128 + mi * 16 + g * 4 + r4;
          float v = acc[mi][ni][r4];
          if constexpr (EPI == 2 || EPI == 3) {
            v += p.bias[m0 + rr];
            if (sel == 0) {
              float sc;
              if constexpr (EPI == 2) sc = ((m0 & 1023) < 512) ? 0.011048543456039806f
                                                               : 0.02209708691207961f;
              else                    sc = (rr < 128) ? 0.011048543456039806f
                                                      : 0.02209708691207961f;
              v *= sc;
            }
          }
          *(unsigned short*)(shb + swz(rr, c * 2)) = f2b(v);
        }
      }
    }
    __syncthreads();

    if constexpr (EPI == 0) {
      unsigned short* C = p.C + (long)bz * p.sCb;
#pragma unroll
      for (int j = 0; j < 16; ++j) {
        const int e = j * 512 + tid;
        const int r = e >> 5, ck = e & 31;
        short8 v = *(const short8*)(shb + swz(r, ck * 16));
        *(short8*)(C + (long)(m0 + r) * p.ldc + n0 + ck * 8) = v;
      }
    } else if constexpr (EPI == 2) {    // ---- QKV lo ----
      const int chb = m0 & 1023;
      const bool cfg0 = chb < 512;
      const int b = bz >> 2, tt = bz & 3;
      const int k0 = n0 >> 8;
      unsigned short* dst = cfg0 ? (sel == 0 ? p.Q0 : sel == 1 ? p.K0 : p.V0t)
                                 : (sel == 0 ? p.Q1 : sel == 1 ? p.K1 : p.V1t);
      if (sel != 2) {
        if (cfg0) {                      // 4x4 patches, d=8192
          const long base = (long)(b * 512) * 8192;
#pragma unroll
          for (int j = 0; j < 16; ++j) {
            const int e = j * 512 + tid;
            const int pi = e >> 9, idx2 = e & 511;
            const int ch = idx2 >> 1, hf = idx2 & 1;
            const int oyL = pi >> 3, ox = pi & 7;
            const int nseq = (tt * 8 + 2 * k0 + oyL) * 8 + ox;
            const int yl = oyL * 4 + hf * 2;
            short4v a = *(const short4v*)(shb + swz(ch, (yl * 32 + ox * 4) * 2));
            short4v b2 = *(const short4v*)(shb + swz(ch, ((yl + 1) * 32 + ox * 4) * 2));
            short8 v = {a[0], a[1], a[2], a[3], b2[0], b2[1], b2[2], b2[3]};
            *(short8*)(dst + base + (long)nseq * 8192 + (chb + ch) * 16 + hf * 8) = v;
          }
        } else {                         // 2x2 patches, d=2048
          const int c2lo = chb - 512;
          const long base = (long)(b * 2048) * 2048;
#pragma unroll
          for (int j = 0; j < 16; ++j) {
            const int e = j * 512 + tid;
            const int pi = e >> 7, cp = e & 127;
            const int oyL = pi >> 4, ox = pi & 15;
            const int nseq = (tt * 16 + 4 * k0 + oyL) * 16 + ox;
            short8 v;
#pragma unroll
            for (int rr = 0; rr < 2; ++rr) {
#pragma unroll
              for (int k = 0; k < 2; ++k) {
                short2v pr = *(const short2v*)(shb +
                    swz(cp * 2 + rr, ((oyL * 2 + k) * 32 + ox * 2) * 2));
                v[rr * 4 + k * 2] = pr[0];
                v[rr * 4 + k * 2 + 1] = pr[1];
              }
            }
            *(short8*)(dst + base + (long)nseq * 2048 + (c2lo + cp * 2) * 4) = v;
          }
        }
      } else {                           // V transposed [f][nseq]
        if (cfg0) {
          const long base = (long)(b * 8192) * 512;
#pragma unroll
          for (int j = 0; j < 16; ++j) {
            const int e = j * 512 + tid;
            const int oyL = e >> 12, fu = e & 4095;
            const int ch = fu >> 4, pp = fu & 15;
            const int py = pp >> 2, px = pp & 3;
            const int yl = oyL * 4 + py;
            short8 v;
#pragma unroll
            for (int ox = 0; ox < 8; ++ox)
              v[ox] = *(const unsigned short*)(shb + swz(ch, (yl * 32 + ox * 4 + px) * 2));
            const long f = (long)(chb + ch) * 16 + pp;
            *(short8*)(dst + base + f * 512 + (tt * 8 + 2 * k0 + oyL) * 8) = v;
          }
        } else {
          const int c2lo = chb - 512;
          const long base = (long)(b * 2048) * 2048;
#pragma unroll
          for (int j = 0; j < 16; ++j) {
            const int e = j * 512 + tid;
            const int he = e & 1, oyL = (e >> 1) & 3, fu = e >> 3;
            const int c2 = fu >> 2, pp = fu & 3;
            const int py = pp >> 1, px = pp & 1;
            const int yl = oyL * 2 + py;
            short8 v;
#pragma unroll
            for (int i = 0; i < 8; ++i) {
              const int ox = he * 8 + i;
              v[i] = *(const unsigned short*)(shb + swz(c2, (yl * 32 + ox * 2 + px) * 2));
            }
            const long f = (long)(c2lo + c2) * 4 + pp;
            *(short8*)(dst + base + f * 2048 + (tt * 16 + 4 * k0 + oyL) * 16 + he * 8) = v;
          }
        }
      }
    } else if constexpr (EPI == 3) {    // ---- QKV hi ----
      const int b = bz >> 2, tt = bz & 3;
      const int k0 = n0 >> 8;
      const int oyA = k0 >> 1, pyb = (k0 & 1) * 4;
      unsigned short* dstA = sel == 0 ? p.Q0 : sel == 1 ? p.K0 : p.V0t;
      unsigned short* dstB = sel == 0 ? p.Q1 : sel == 1 ? p.K1 : p.V1t;
      if (sel != 2) {
#pragma unroll
        for (int j = 0; j < 16; ++j) {
          const int e = j * 512 + tid;
          if (e < 4096) {                // cfg0: 8x8 patches
            const int ox = e >> 9, cy = e & 511;
            const int ch = cy >> 2, yl = cy & 3;
            const int nseq = 256 + (tt * 8 + oyA) * 8 + ox;
            short8 v = *(const short8*)(shb + swz(ch, (yl * 64 + ox * 8) * 2));
            *(short8*)(dstA + ((long)(b * 512 + nseq)) * 8192 + ch * 64 + (pyb + yl) * 8) = v;
          } else {                       // cfg1: 4x4 patches
            const int ee = e - 4096;
            const int ox = ee >> 8, cc = ee & 255;
            const int c2 = cc >> 1, hf = cc & 1;
            const int nseq = 1024 + (tt * 16 + k0) * 16 + ox;
            short8 v;
#pragma unroll
            for (int k = 0; k < 2; ++k) {
              short4v a = *(const short4v*)(shb +
                  swz(128 + c2, ((hf * 2 + k) * 64 + ox * 4) * 2));
              v[k * 4] = a[0]; v[k * 4 + 1] = a[1]; v[k * 4 + 2] = a[2]; v[k * 4 + 3] = a[3];
            }
            *(short8*)(dstB + ((long)(b * 2048 + nseq)) * 2048 + c2 * 16 + hf * 8) = v;
          }
        }
      } else {
#pragma unroll
        for (int j = 0; j < 16; ++j) {
          const int e = j * 512 + tid;
          if (e < 4096) {                // cfg0 V
            const int ch = e >> 5, yl = (e >> 3) & 3, px = e & 7;
            short8 v;
#pragma unroll
            for (int ox = 0; ox < 8; ++ox)
              v[ox] = *(const unsigned short*)(shb + swz(ch, (yl * 64 + ox * 8 + px) * 2));
            const long f = (long)ch * 64 + (pyb + yl) * 8 + px;
            *(short8*)(dstA + ((long)b * 8192 + f) * 512 + 256 + (tt * 8 + oyA) * 8) = v;
          } else {                       // cfg1 V
            const int ee = e - 4096;
            const int he = ee & 1, fu = ee >> 1;
            const int c2 = fu >> 4, pp = fu & 15;
            const int py = pp >> 2, px = pp & 3;
            short8 v;
#pragma unroll
            for (int i = 0; i < 8; ++i) {
              const int x = (he * 8 + i) * 4 + px;
              v[i] = *(const unsigned short*)(shb + swz(128 + c2, (py * 64 + x) * 2));
            }
            const long f = (long)c2 * 16 + pp;
            *(short8*)(dstB + ((long)b * 2048 + f) * 2048 + 1024 + (tt * 16 + k0) * 16 + he * 8) = v;
          }
        }
      }
    } else if constexpr (EPI == 4) {    // ---- PV0 tile -> padded NHWC (cfg0) ----
      const int b = bz;
      if (m0 == 0) {                     // lo rows: 4x4 patches, CinLo ch 0..511
        const int chbase = n0 >> 4;
        unsigned short* dst = p.Q0;      // CinP_lo
#pragma unroll
        for (int j = 0; j < 16; ++j) {
          const int e = j * 512 + tid;
          const int hf = e & 1, pp = (e >> 1) & 15, rr = e >> 5;
          const int t = rr >> 6, oh = (rr >> 3) & 7, ow = rr & 7;
          const int bt = b * 4 + t;
          const int py = pp >> 2, px = pp & 3;
          short8 v;
#pragma unroll
          for (int i = 0; i < 8; ++i)
            v[i] = *(const unsigned short*)(shb + swz(rr, ((hf * 8 + i) * 16 + pp) * 2));
          *(short8*)(dst + (((long)bt * 34 + oh * 4 + py + 1) * 34 + ow * 4 + px + 1) * 1024
                     + chbase + hf * 8) = v;
        }
      } else {                           // hi rows: 8x8 patches, CinHi ch 0..127
        const int chbase = n0 >> 6;
        unsigned short* dst = p.Q1;      // CinP_hi
#pragma unroll
        for (int j = 0; j < 32; ++j) {
          const int e = j * 512 + tid;
          const int pp = e & 63, rr = e >> 6;
          const int t = rr >> 6, oh = (rr >> 3) & 7, ow = rr & 7;
          const int bt = b * 4 + t;
          const int py = pp >> 3, px = pp & 7;
          short4v v;
#pragma unroll
          for (int i = 0; i < 4; ++i)
            v[i] = *(const unsigned short*)(shb + swz(rr, (i * 64 + pp) * 2));
          *(short4v*)(dst + (((long)bt * 66 + oh * 8 + py + 1) * 66 + ow * 8 + px + 1) * 256
                      + chbase) = v;
        }
      }
    } else if constexpr (EPI == 5) {    // ---- PV1 tile -> padded NHWC (cfg1) ----
      const int b = bz;
      if (m0 < 1024) {                   // lo: 2x2 patches, CinLo ch 512..1023
        const int chbase = n0 >> 2;
        unsigned short* dst = p.Q0;
#pragma unroll
        for (int j = 0; j < 16; ++j) {
          const int e = j * 512 + tid;
          const int ch8 = e & 7, pp = (e >> 3) & 3, rr = e >> 5;
          const int n = m0 + rr;
          const int t = n >> 8, oh = (n >> 4) & 15, ow = n & 15;
          const int bt = b * 4 + t;
          const int py = pp >> 1, px = pp & 1;
          short8 v;
#pragma unroll
          for (int i = 0; i < 8; ++i)
            v[i] = *(const unsigned short*)(shb + swz(rr, ((ch8 * 8 + i) * 4 + pp) * 2));
          *(short8*)(dst + (((long)bt * 34 + oh * 2 + py + 1) * 34 + ow * 2 + px + 1) * 1024
                     + 512 + chbase + ch8 * 8) = v;
        }
      } else {                           // hi: 4x4 patches, CinHi ch 128..255
        const int chbase = n0 >> 4;
        unsigned short* dst = p.Q1;
#pragma unroll
        for (int j = 0; j < 16; ++j) {
          const int e = j * 512 + tid;
          const int hf = e & 1, pp = (e >> 1) & 15, rr = e >> 5;
          const int m = m0 + rr - 1024;
          const int t = m >> 8, oh = (m >> 4) & 15, ow = m & 15;
          const int bt = b * 4 + t;
          const int py = pp >> 2, px = pp & 3;
          short8 v;
#pragma unroll
          for (int i = 0; i < 8; ++i)
            v[i] = *(const unsigned short*)(shb + swz(rr, ((hf * 8 + i) * 16 + pp) * 2));
          *(short8*)(dst + (((long)bt * 66 + oh * 4 + py + 1) * 66 + ow * 4 + px + 1) * 256
                     + 128 + chbase + hf * 8) = v;
        }
      }
    }
  }
}

// ---------------------------------------------------------------------------
// 3x3 conv as im2col GEMM — R15 core (best measured for conv): BK=32,
// 4-buffer ring, counted vmcnt(4)/0, ONE barrier per K-tile, next-tile
// af/bf register rotation. PARTIAL: bf16 partial slabs.
// ---------------------------------------------------------------------------
template<int H, int W, int CIN, int KS, bool PARTIAL>
__global__ __launch_bounds__(512) void conv256(const unsigned short* __restrict__ Cinp,
                                               const unsigned short* __restrict__ Wt,
                                               const float* __restrict__ bias,
                                               float* __restrict__ out,
                                               unsigned short* __restrict__ P0,
                                               unsigned short* __restrict__ P1) {
  constexpr int HP = H + 2, WP = W + 2;
  constexpr int CC = CIN / KS;
  constexpr int NT = 9 * CC / 32;
  __shared__ __align__(16) unsigned short LDS[65536];
  const int tid = threadIdx.x;
  const int wv = tid >> 6, lane = tid & 63;
  const int wm = wv >> 2, wn = wv & 3;
  const int g = lane >> 4, l16 = lane & 15;
  int bx = blockIdx.x, by = blockIdx.y, bz = blockIdx.z;
  xcd_remap(bx, by, bz);
  const int bt = bz / KS, ks = bz % KS;
  const int n0 = bx * 256;

  const int r0 = tid >> 2;
  const int cs = (tid & 3) ^ ((r0 >> 1) & 3);
  const unsigned short* wA0 = Wt + (long)r0 * CIN + ks * CC + cs * 8;
  const unsigned short* wA1 = wA0 + (long)128 * CIN;
  const int p0 = n0 + r0, p1 = p0 + 128;
  const int y0p = p0 / W, x0p = p0 % W;
  const int y1p = p1 / W, x1p = p1 % W;
  const unsigned short* cB = Cinp + (long)bt * HP * WP * CIN + ks * CC + cs * 8;
  const unsigned short* pB0 = cB + ((long)y0p * WP + x0p) * CIN;
  const unsigned short* pB1 = cB + ((long)y1p * WP + x1p) * CIN;
  unsigned short* const lds0 = (unsigned short*)LDS;
  const int wbase = wv * 512;

  auto STAGE_A = [&](int t) {
    unsigned short* d = lds0 + (t & 3) * 16384;
    const int tap = t >> 3, tc = (t & 7) * 32;
    const long off = (long)tap * (256L * CIN) + tc;
    glds16(wA0 + off, d + wbase);
    glds16(wA1 + off, d + 4096 + wbase);
  };
  auto STAGE_B = [&](int t) {
    unsigned short* d = lds0 + (t & 3) * 16384 + 8192;
    const int tap = t >> 3, tc = (t & 7) * 32;
    const int ky = tap / 3, kx = tap - ky * 3;
    const long off = ((long)ky * WP + kx) * CIN + tc;
    glds16(pB0 + off, d + wbase);
    glds16(pB1 + off, d + 4096 + wbase);
  };

  STAGE_A(0); STAGE_B(0); STAGE_A(1); STAGE_B(1); STAGE_A(2); STAGE_B(2);

  floatx4 acc[8][4];
  const floatx4 z4 = {0.f, 0.f, 0.f, 0.f};
#pragma unroll
  for (int i = 0; i < 8; ++i)
#pragma unroll
    for (int j = 0; j < 4; ++j) acc[i][j] = z4;

  const int loff = l16 * 32 + ((g ^ ((l16 >> 1) & 3)) * 8);
  const int aRowB = wm * 128;

  asm volatile("s_waitcnt vmcnt(8)" ::: "memory");
  __builtin_amdgcn_s_barrier();
  short8 bf[4], af[4];
#pragma unroll
  for (int ni = 0; ni < 4; ++ni)
    bf[ni] = *(const short8*)(lds0 + 8192 + (wn * 64 + ni * 16) * 32 + loff);
#pragma unroll
  for (int mi = 0; mi < 4; ++mi)
    af[mi] = *(const short8*)(lds0 + (aRowB + mi * 16) * 32 + loff);

  for (int t = 0; t < NT; ++t) {
    const unsigned short* As = lds0 + (t & 3) * 16384;
    const unsigned short* AsN = lds0 + ((t + 1) & 3) * 16384;
    if (t < NT - 2) asm volatile("s_waitcnt vmcnt(4)" ::: "memory");
    else            asm volatile("s_waitcnt vmcnt(0)" ::: "memory");
    __builtin_amdgcn_s_barrier();
    __builtin_amdgcn_sched_barrier(0);
    if (t + 3 < NT) STAGE_A(t + 3);
    short8 ag[4];
#pragma unroll
    for (int mi = 0; mi < 4; ++mi)
      ag[mi] = *(const short8*)(As + (aRowB + 64 + mi * 16) * 32 + loff);
    __builtin_amdgcn_s_setprio(1);
#pragma unroll
    for (int mi = 0; mi < 4; ++mi)
#pragma unroll
      for (int ni = 0; ni < 4; ++ni)
        acc[mi][ni] = __builtin_amdgcn_mfma_f32_16x16x32_bf16(af[mi], bf[ni], acc[mi][ni], 0, 0, 0);
    __builtin_amdgcn_s_setprio(0);
    if (t + 3 < NT) STAGE_B(t + 3);
    short8 bfN[4], afN[4];
    if (t + 1 < NT) {
      const unsigned short* BsN = AsN + 8192;
#pragma unroll
      for (int ni = 0; ni < 4; ++ni)
        bfN[ni] = *(const short8*)(BsN + (wn * 64 + ni * 16) * 32 + loff);
#pragma unroll
      for (int mi = 0; mi < 4; ++mi)
        afN[mi] = *(const short8*)(AsN + (aRowB + mi * 16) * 32 + loff);
    }
    __builtin_amdgcn_s_setprio(1);
#pragma unroll
    for (int mi = 0; mi < 4; ++mi)
#pragma unroll
      for (int ni = 0; ni < 4; ++ni)
        acc[4 + mi][ni] = __builtin_amdgcn_mfma_f32_16x16x32_bf16(ag[mi], bf[ni], acc[4 + mi][ni], 0, 0, 0);
    __builtin_amdgcn_s_setprio(0);
    if (t + 1 < NT) {
#pragma unroll
      for (int i = 0; i < 4; ++i) { bf[i] = bfN[i]; af[i] = afN[i]; }
    }
  }

  if constexpr (!PARTIAL) {
#pragma unroll
    for (int mi = 0; mi < 8; ++mi) {
#pragma unroll
      for (int ni = 0; ni < 4; ++ni) {
        const int pn = n0 + wn * 64 + ni * 16 + l16;
        const int y = pn / W, x = pn % W;
#pragma unroll
        for (int r4 = 0; r4 < 4; ++r4) {
          const int co = wm * 128 + mi * 16 + g * 4 + r4;
          float v = acc[mi][ni][r4] + bias[co];
          v = v > 0.f ? v : 0.2f * v;
          out[(((long)bt * 256 + co) * H + y) * W + x] = v;
        }
      }
    }
  } else {
    unsigned short* pout = (ks < 2 ? P0 : P1) + (long)(ks & 1) * (16L * 256 * H * W);
#pragma unroll
    for (int mi = 0; mi < 8; ++mi) {
#pragma unroll
      for (int ni = 0; ni < 4; ++ni) {
        const int pn = n0 + wn * 64 + ni * 16 + l16;
        const int y = pn / W, x = pn % W;
#pragma unroll
        for (int r4 = 0; r4 < 4; ++r4) {
          const int co = wm * 128 + mi * 16 + g * 4 + r4;
          pout[(((long)bt * 256 + co) * H + y) * W + x] = f2b(acc[mi][ni][r4]);
        }
      }
    }
  }
}

// ---------------------------------------------------------------------------
// Row softmax in-place on bf16 rows of length L. One wave per row.
// ---------------------------------------------------------------------------
template<int L>
__global__ __launch_bounds__(256) void softmax_rows(unsigned short* S) {
  const int w = threadIdx.x >> 6, lane = threadIdx.x & 63;
  const long row = (long)blockIdx.x * 4 + w;
  unsigned short* R = S + row * L;
  constexpr int NC = L / 64;
  float v[NC];
  float m = -1e30f;
#pragma unroll
  for (int i = 0; i < NC; ++i) { v[i] = b2f(R[i * 64 + lane]); m = fmaxf(m, v[i]); }
#pragma unroll
  for (int off = 32; off; off >>= 1) m = fmaxf(m, __shfl_xor(m, off, 64));
  float s = 0.f;
#pragma unroll
  for (int i = 0; i < NC; ++i) { v[i] = __expf(v[i] - m); s += v[i]; }
#pragma unroll
  for (int off = 32; off; off >>= 1) s += __shfl_xor(s, off, 64);
  const float inv = 1.0f / s;
#pragma unroll
  for (int i = 0; i < NC; ++i) R[i * 64 + lane] = f2b(v[i] * inv);
}

// ---------------------------------------------------------------------------
// S0: sum 16 bf16 split-K slabs [b*16+ks][512][512] -> softmax -> bf16
// ---------------------------------------------------------------------------
__global__ __launch_bounds__(256) void softmax_red16(const unsigned short* __restrict__ P,
                                                     unsigned short* __restrict__ S) {
  const int w = threadIdx.x >> 6, lane = threadIdx.x & 63;
  const int rowg = blockIdx.x * 4 + w;
  const int b = rowg >> 9, n = rowg & 511;
  const unsigned short* base = P + ((long)b * 16) * 262144 + (long)n * 512 + lane;
  float v[8];
#pragma unroll
  for (int i = 0; i < 8; ++i) {
    float s = 0.f;
#pragma unroll
    for (int ks = 0; ks < 16; ++ks) s += b2f(base[(long)ks * 262144 + i * 64]);
    v[i] = s;
  }
  float m = -1e30f;
#pragma unroll
  for (int i = 0; i < 8; ++i) m = fmaxf(m, v[i]);
#pragma unroll
  for (int off = 32; off; off >>= 1) m = fmaxf(m, __shfl_xor(m, off, 64));
  float s = 0.f;
#pragma unroll
  for (int i = 0; i < 8; ++i) { v[i] = __expf(v[i] - m); s += v[i]; }
#pragma unroll
  for (int off = 32; off; off >>= 1) s += __shfl_xor(s, off, 64);
  const float inv = 1.0f / s;
  unsigned short* R = S + (long)rowg * 512;
#pragma unroll
  for (int i = 0; i < 8; ++i) R[i * 64 + lane] = f2b(v[i] * inv);
}

// ---------------------------------------------------------------------------
// Combined x_lo/x_hi NCHW fp32 -> pixel-major bf16 transpose (1 dispatch).
// ---------------------------------------------------------------------------
__global__ __launch_bounds__(256) void xt_both(const float* __restrict__ x_lo,
                                               unsigned short* __restrict__ xt_lo,
                                               const float* __restrict__ x_hi,
                                               unsigned short* __restrict__ xt_hi) {
  __shared__ unsigned short tile[64 * 65];
  const int tid = threadIdx.x;
  const int blk = blockIdx.x;
  const float* x; unsigned short* xt; int NPIX, bxx, byy, bzz;
  if (blk < 1024) {
    x = x_lo; xt = xt_lo; NPIX = 1024;
    bxx = blk & 15; byy = (blk >> 4) & 3; bzz = blk >> 6;
  } else {
    const int q = blk - 1024;
    x = x_hi; xt = xt_hi; NPIX = 4096;
    bxx = q & 63; byy = (q >> 6) & 3; bzz = q >> 8;
  }
  const int ch0 = byy * 64;
  const long pix0 = (long)bxx * 64;
  const float* src = x + ((long)bzz * 256 + ch0) * NPIX + pix0;
#pragma unroll
  for (int i = 0; i < 16; ++i) {
    const int lin = i * 256 + tid;
    const int ch = lin >> 6, px = lin & 63;
    tile[ch * 65 + px] = f2b(src[(long)ch * NPIX + px]);
  }
  __syncthreads();
  unsigned short* dst = xt + ((long)bzz * NPIX + pix0) * 256 + ch0;
#pragma unroll
  for (int i = 0; i < 16; ++i) {
    const int lin = i * 256 + tid;
    const int px = lin >> 6, ch = lin & 63;
    dst[(long)px * 256 + ch] = tile[ch * 65 + px];
  }
}

// ---------------------------------------------------------------------------
// Combined QKV weight prep (lo 3072 blocks + hi 768 blocks, 1 dispatch).
// ---------------------------------------------------------------------------
__global__ void prep_qkv_both(const float* wq_lo, const float* wk_lo, const float* wv_lo,
                              const float* bq_lo, const float* bk_lo, const float* bv_lo,
                              unsigned short* Wcat_lo, float* Bcat_lo,
                              const float* wq_hi, const float* wk_hi, const float* wv_hi,
                              const float* bq_hi, const float* bk_hi, const float* bv_hi,
                              unsigned short* Wcat_hi, float* Bcat_hi) {
  const int blk = blockIdx.x;
  const float *wq, *wk, *wv, *bq, *bk, *bv;
  unsigned short* Wcat; float* Bcat; int CO, idx;
  if (blk < 3072) {
    wq = wq_lo; wk = wk_lo; wv = wv_lo; bq = bq_lo; bk = bk_lo; bv = bv_lo;
    Wcat = Wcat_lo; Bcat = Bcat_lo; CO = 1024;
    idx = blk * 256 + threadIdx.x;
  } else {
    wq = wq_hi; wk = wk_hi; wv = wv_hi; bq = bq_hi; bk = bk_hi; bv = bv_hi;
    Wcat = Wcat_hi; Bcat = Bcat_hi; CO = 256;
    idx = (blk - 3072) * 256 + threadIdx.x;
  }
  const int n = 3 * CO * 256;
  if (idx < n) {
    const int sel = idx / (CO * 256);
    const int r = idx - sel * CO * 256;
    const float* wsel = sel == 0 ? wq : (sel == 1 ? wk : wv);
    Wcat[idx] = f2b(wsel[r]);
  }
  if (idx < 3 * CO) {
    const int sel = idx / CO;
    const int r = idx - sel * CO;
    const float* bsel = sel == 0 ? bq : (sel == 1 ? bk : bv);
    Bcat[idx] = bsel[r];
  }
}

// ---------------------------------------------------------------------------
// Combined conv weight prep: wo [256][CIN][9] fp32 -> Wt [9][256][CIN] bf16.
// ---------------------------------------------------------------------------
__global__ __launch_bounds__(256) void prep_conv_both(const float* __restrict__ wo_lo,
                                                      unsigned short* __restrict__ Wt_lo,
                                                      const float* __restrict__ wo_hi,
                                                      unsigned short* __restrict__ Wt_hi) {
  __shared__ unsigned short T[9216];
  const int blk = blockIdx.x;
  const int tid = threadIdx.x;
  if (blk < 256) {                 // lo: OC=1, CIN=1024
    const int o0 = blk;
    const float* src = wo_lo + (long)o0 * 1024 * 9;
    for (int j = tid; j < 9216; j += 256) {
      const int t9 = j % 9, r = j / 9;
      T[t9 * 1024 + r] = f2b(src[j]);
    }
    __syncthreads();
#pragma unroll
    for (int t9 = 0; t9 < 9; ++t9)
      for (int j = tid; j < 1024; j += 256)
        Wt_lo[((long)t9 * 256 + o0) * 1024 + j] = T[t9 * 1024 + j];
  } else {                         // hi: OC=4, CIN=256
    const int o0 = (blk - 256) * 4;
    const float* src = wo_hi + (long)o0 * 256 * 9;
    for (int j = tid; j < 9216; j += 256) {
      const int t9 = j % 9, r = j / 9;
      T[t9 * 1024 + r] = f2b(src[j]);
    }
    __syncthreads();
#pragma unroll
    for (int t9 = 0; t9 < 9; ++t9)
      for (int j = tid; j < 1024; j += 256) {
        const int oo = j >> 8, i = j & 255;
        Wt_hi[((long)t9 * 256 + o0 + oo) * 256 + i] = T[t9 * 1024 + j];
      }
  }
}

// ---------------------------------------------------------------------------
// Combined halo-border zeroing for both padded NHWC buffers (1 dispatch).
// ---------------------------------------------------------------------------
__global__ __launch_bounds__(256) void zero_both(unsigned short* lo, unsigned short* hi) {
  const int blk = blockIdx.x;
  unsigned short* buf; int HP, WP, C; long i;
  if (blk < 1056) { buf = lo; HP = 34; WP = 34; C = 1024; i = (long)blk * 256 + threadIdx.x; }
  else            { buf = hi; HP = 66; WP = 66; C = 256;  i = (long)(blk - 1056) * 256 + threadIdx.x; }
  const int per_px = C >> 3;
  const int strip = 2 * WP + 2 * (HP - 2);
  const long tot = (long)16 * strip * per_px;
  if (i >= tot) return;
  const int c8 = (int)(i % per_px);
  const long r = i / per_px;
  const int s = (int)(r % strip);
  const int bt = (int)(r / strip);
  int y, x;
  if (s < WP) { y = 0; x = s; }
  else if (s < 2 * WP) { y = HP - 1; x = s - WP; }
  else if (s < 2 * WP + (HP - 2)) { y = s - 2 * WP + 1; x = 0; }
  else { y = s - 2 * WP - (HP - 2) + 1; x = WP - 1; }
  const short8 z = {0, 0, 0, 0, 0, 0, 0, 0};
  *(short8*)(buf + (((long)bt * HP + y) * WP + x) * C + c8 * 8) = z;
}

// ---------------------------------------------------------------------------
// Sum 4 bf16 conv partial slabs (2 in P0, 2 in P1) + bias + leaky-relu -> out
// ---------------------------------------------------------------------------
__global__ __launch_bounds__(256) void reduce_lrelu(const unsigned short* __restrict__ P0,
                                                    const unsigned short* __restrict__ P1,
                                                    const float* __restrict__ bias,
                                                    float* __restrict__ out) {
  const long i = (long)blockIdx.x * 256 + threadIdx.x;
  const long flat = i * 8;
  constexpr long SL = 4194304;
  short8 a = *(const short8*)(P0 + flat);
  short8 b = *(const short8*)(P0 + SL + flat);
  short8 c = *(const short8*)(P1 + flat);
  short8 d = *(const short8*)(P1 + SL + flat);
  const int co = ((int)(flat >> 10)) & 255;
  const float bv = bias[co];
  floatx4 r0, r1;
#pragma unroll
  for (int j = 0; j < 8; ++j) {
    float v = b2f((unsigned short)a[j]) + b2f((unsigned short)b[j]) +
              b2f((unsigned short)c[j]) + b2f((unsigned short)d[j]) + bv;
    v = v > 0.f ? v : 0.2f * v;
    if (j < 4) r0[j] = v; else r1[j - 4] = v;
  }
  *(floatx4*)(out + flat) = r0;
  *(floatx4*)(out + flat + 4) = r1;
}

// ---------------------------------------------------------------------------
extern "C" void kernel_launch(void* const* d_in, const int* in_sizes, int n_in,
                              void* d_out, int out_size, void* d_ws, size_t ws_size,
                              hipStream_t stream) {
  (void)in_sizes; (void)n_in; (void)out_size; (void)ws_size;
  const float* x_lo = (const float*)d_in[0];
  const float* x_hi = (const float*)d_in[1];
  const float* wq_lo = (const float*)d_in[3];
  const float* bq_lo = (const float*)d_in[4];
  const float* wk_lo = (const float*)d_in[5];
  const float* bk_lo = (const float*)d_in[6];
  const float* wv_lo = (const float*)d_in[7];
  const float* bv_lo = (const float*)d_in[8];
  const float* wq_hi = (const float*)d_in[9];
  const float* bq_hi = (const float*)d_in[10];
  const float* wk_hi = (const float*)d_in[11];
  const float* bk_hi = (const float*)d_in[12];
  const float* wv_hi = (const float*)d_in[13];
  const float* bv_hi = (const float*)d_in[14];
  const float* wo_lo = (const float*)d_in[15];
  const float* bo_lo = (const float*)d_in[16];
  const float* wo_hi = (const float*)d_in[17];
  const float* bo_hi = (const float*)d_in[18];
  float* out = (float*)d_out;

  char* ws = (char*)d_ws;
  const long B0 = 33554432;
  unsigned short* Qp0 = (unsigned short*)(ws);            // later: CinP_lo (+ Kp0 spill)
  unsigned short* Kp0 = (unsigned short*)(ws + B0);
  unsigned short* V0t = (unsigned short*)(ws + 2 * B0);   // later: conv partials PC0
  unsigned short* Qp1 = (unsigned short*)(ws + 3 * B0);   // later: CinP_hi (+ Kp1 spill)
  unsigned short* Kp1 = (unsigned short*)(ws + 4 * B0);
  unsigned short* V1t = (unsigned short*)(ws + 5 * B0);   // later: conv partials PC1
  char* ptr = ws + 6 * B0;
  unsigned short* S0 = (unsigned short*)ptr;     ptr += 2097152;
  unsigned short* Xt_lo = (unsigned short*)ptr;  ptr += 8388608;
  unsigned short* Xt_hi = (unsigned short*)ptr;  ptr += 33554432;   // later: S0p, then S1
  unsigned short* Wcat_lo = (unsigned short*)ptr; ptr += 1572864;
  unsigned short* Wcat_hi = (unsigned short*)ptr; ptr += 393216;
  float* Bcat_lo = (float*)ptr;                  ptr += 12288;
  float* Bcat_hi = (float*)ptr;                  ptr += 3072;
  unsigned short* Wt_lo = (unsigned short*)ptr;  ptr += 4718592;
  unsigned short* Wt_hi = (unsigned short*)ptr;  ptr += 1179648;
  unsigned short* S0p = Xt_hi;          // S0 bf16 partials (33.5 MB), dead after red16
  unsigned short* S1 = Xt_hi;           // S1 written after red16 consumed S0p
  unsigned short* CinP_lo = Qp0;        // 37.9 MB: Qp0 + spill into Kp0 (both dead)
  unsigned short* CinP_hi = Qp1;        // 35.7 MB: Qp1 + spill into Kp1 (both dead)
  unsigned short* PC0 = V0t;            // conv_lo bf16 partial slabs 0,1
  unsigned short* PC1 = V1t;            // slabs 2,3

  // --- fused weight/input prep (3 dispatches) ---
  prep_qkv_both<<<3840, 256, 0, stream>>>(
      wq_lo, wk_lo, wv_lo, bq_lo, bk_lo, bv_lo, Wcat_lo, Bcat_lo,
      wq_hi, wk_hi, wv_hi, bq_hi, bk_hi, bv_hi, Wcat_hi, Bcat_hi);
  prep_conv_both<<<320, 256, 0, stream>>>(wo_lo, Wt_lo, wo_hi, Wt_hi);
  xt_both<<<5120, 256, 0, stream>>>(x_lo, Xt_lo, x_hi, Xt_hi);

  // --- QKV projections (1x1 conv as TN-GEMM), staged coalesced scatter ---
  {
    GemmP p{};
    p.A = Wcat_lo; p.B = Xt_lo; p.sAb = 0; p.sBb = 1024L * 256;
    p.lda = 256; p.ldb = 256; p.K = 256;
    p.bias = Bcat_lo;
    p.Q0 = Qp0; p.K0 = Kp0; p.V0t = V0t; p.Q1 = Qp1; p.K1 = Kp1; p.V1t = V1t;
    gemm256<2><<<dim3(4, 12, 16), 512, 0, stream>>>(p);
    p.A = Wcat_hi; p.B = Xt_hi; p.sBb = 4096L * 256; p.bias = Bcat_hi;
    gemm256<3><<<dim3(16, 3, 16), 512, 0, stream>>>(p);
  }

  // --- S0 scores: n=512, d=8192 (split-K 16, bf16 partials) + softmax ---
  {
    GemmP s{};
    s.A = Qp0; s.B = Kp0; s.sAb = 512L * 8192; s.sBb = 512L * 8192;
    s.lda = 8192; s.ldb = 8192; s.K = 8192;
    s.C = S0p; s.sCb = 262144; s.ldc = 512;
    gemm256<1><<<dim3(2, 2, 64), 512, 0, stream>>>(s);
    softmax_red16<<<512, 256, 0, stream>>>(S0p, S0);
  }

  // --- S1 scores: n=2048, d=2048 (into Xt_hi region) + softmax ---
  {
    GemmP s{};
    s.A = Qp1; s.B = Kp1; s.sAb = 2048L * 2048; s.sBb = 2048L * 2048;
    s.lda = 2048; s.ldb = 2048; s.K = 2048;
    s.C = S1; s.sCb = 2048L * 2048; s.ldc = 2048;
    gemm256<0><<<dim3(8, 8, 4), 512, 0, stream>>>(s);
    softmax_rows<2048><<<2048, 256, 0, stream>>>(S1);
  }

  // --- halo zeroing, then PV with fused repack ---
  zero_both<<<1576, 256, 0, stream>>>(CinP_lo, CinP_hi);
  {
    GemmP pv{};
    pv.A = S0; pv.B = V0t; pv.sAb = 512L * 512; pv.sBb = 8192L * 512;
    pv.lda = 512; pv.ldb = 512; pv.K = 512;
    pv.Q0 = CinP_lo; pv.Q1 = CinP_hi;
    gemm256<4><<<dim3(32, 2, 4), 512, 0, stream>>>(pv);
  }
  {
    GemmP pv{};
    pv.A = S1; pv.B = V1t; pv.sAb = 2048L * 2048; pv.sBb = 2048L * 2048;
    pv.lda = 2048; pv.ldb = 2048; pv.K = 2048;
    pv.Q0 = CinP_lo; pv.Q1 = CinP_hi;
    gemm256<5><<<dim3(8, 8, 4), 512, 0, stream>>>(pv);
  }

  // --- 3x3 convs: R15 BK=32 core (best measured for conv) ---
  conv256<32, 32, 1024, 4, true><<<dim3(4, 1, 64), 512, 0, stream>>>(
      CinP_lo, Wt_lo, bo_lo, out, PC0, PC1);
  reduce_lrelu<<<2048, 256, 0, stream>>>(PC0, PC1, bo_lo, out);
  conv256<64, 64, 256, 1, false><<<dim3(16, 1, 16), 512, 0, stream>>>(
      CinP_hi, Wt_hi, bo_hi, out + 4194304, nullptr, nullptr);
}

// Round 18
// 512.541 us; speedup vs baseline: 1.0080x; 1.0080x over previous
//
#include <hip/hip_runtime.h>
#include <hip/hip_bf16.h>
#include <stdint.h>

typedef __attribute__((ext_vector_type(8))) short short8;
typedef __attribute__((ext_vector_type(4))) short short4v;
typedef __attribute__((ext_vector_type(2))) short short2v;
typedef __attribute__((ext_vector_type(4))) float floatx4;

__device__ __forceinline__ unsigned short f2b(float f) {
  unsigned u = __builtin_bit_cast(unsigned, f);
  unsigned r = u + 0x7fffu + ((u >> 16) & 1u);
  return (unsigned short)(r >> 16);
}
__device__ __forceinline__ float b2f(unsigned short h) {
  unsigned u = ((unsigned)h) << 16;
  return __builtin_bit_cast(float, u);
}
__device__ __forceinline__ void glds16(const unsigned short* src, unsigned short* dst) {
  __builtin_amdgcn_global_load_lds((const __attribute__((address_space(1))) void*)src,
                                   (__attribute__((address_space(3))) void*)dst, 16, 0, 0);
}
// epilogue LDS swizzle: row r (0..255), o = byte offset in 512B row.
__device__ __forceinline__ int swz(int r, int o) {
  return (r << 9) + (o ^ ((((o >> 7) & 3) ^ (r & 7)) << 4));
}
// T1: bijective XCD-contiguous work remap (requires nwg % 8 == 0).
__device__ __forceinline__ void xcd_remap(int& bx, int& by, int& bz) {
  const int gx = gridDim.x, gy = gridDim.y;
  const int nwg = gx * gy * (int)gridDim.z;
  int lin = bx + gx * (by + gy * bz);
  lin = (lin & 7) * (nwg >> 3) + (lin >> 3);
  bx = lin % gx; const int r = lin / gx;
  by = r % gy; bz = r / gy;
}

// ---------------------------------------------------------------------------
// 256x256-tile TN GEMM core, BK=64: 512 thr = 8 waves (2Mx4N); 2-buffer ring
// (2x64KB); per tile: vmcnt(0) [full-tile latency cover] -> barrier ->
// stage(t+1) -> {kk0: read+64 MFMA; kk1: read+64 MFMA}. 1 barrier / 64 MFMA.
// EPI 0: staged bf16 C. EPI 1: split-K(16) bf16 partials. EPI 2/3: QKV scatter.
// EPI 4/5: PV tiles -> padded NHWC conv inputs (fused from_patches).
// ---------------------------------------------------------------------------
struct GemmP {
  const unsigned short* A;
  const unsigned short* B;
  long sAb, sBb;
  int lda, ldb, K;
  unsigned short* C; long sCb; int ldc;
  const float* bias;
  unsigned short *Q0, *K0, *V0t, *Q1, *K1, *V1t;
};

template<int EPI>
__global__ __launch_bounds__(512) void gemm256(GemmP p) {
  __shared__ __align__(16) unsigned short LDS[65536];
  const int tid = threadIdx.x;
  const int wv = tid >> 6, lane = tid & 63;
  const int wm = wv >> 2, wn = wv & 3;
  const int g = lane >> 4, l16 = lane & 15;
  int bx = blockIdx.x, by = blockIdx.y, bz = blockIdx.z;
  xcd_remap(bx, by, bz);
  const int m0 = by * 256, n0 = bx * 256;

  int bb = bz, koff = 0, Keff = p.K;
  if constexpr (EPI == 1) { bb = bz >> 4; koff = (bz & 15) * (p.K >> 4); Keff = p.K >> 4; }
  const unsigned short* Ab = p.A + (long)bb * p.sAb + (long)m0 * p.lda + koff;
  const unsigned short* Bb = p.B + (long)bb * p.sBb + (long)n0 * p.ldb + koff;
  const int NT = Keff >> 6;

  const int r0 = tid >> 3;
  const int cs8 = (tid & 7) ^ (r0 & 7);
  const unsigned short* aS[4];
  const unsigned short* bS[4];
#pragma unroll
  for (int i = 0; i < 4; ++i) {
    aS[i] = Ab + (long)(r0 + 64 * i) * p.lda + cs8 * 8;
    bS[i] = Bb + (long)(r0 + 64 * i) * p.ldb + cs8 * 8;
  }
  unsigned short* const lds0 = (unsigned short*)LDS;
  const int wbase = wv * 512;

  auto STAGE = [&](int t) {
    unsigned short* d = lds0 + (t & 1) * 32768;
    const long ko = (long)t * 64;
#pragma unroll
    for (int i = 0; i < 4; ++i) glds16(aS[i] + ko, d + i * 4096 + wbase);
#pragma unroll
    for (int i = 0; i < 4; ++i) glds16(bS[i] + ko, d + 16384 + i * 4096 + wbase);
  };

  STAGE(0);

  floatx4 acc[8][4];
  const floatx4 z4 = {0.f, 0.f, 0.f, 0.f};
#pragma unroll
  for (int i = 0; i < 8; ++i)
#pragma unroll
    for (int j = 0; j < 4; ++j) acc[i][j] = z4;

  const int lmask = l16 & 7;
  const int loff0 = l16 * 64 + ((g ^ lmask) * 8);
  const int aRowB = wm * 128;

  for (int t = 0; t < NT; ++t) {
    const unsigned short* As = lds0 + (t & 1) * 32768;
    const unsigned short* Bs = As + 16384;
    asm volatile("s_waitcnt vmcnt(0)" ::: "memory");
    __builtin_amdgcn_s_barrier();
    __builtin_amdgcn_sched_barrier(0);
    if (t + 1 < NT) STAGE(t + 1);
#pragma unroll
    for (int kk = 0; kk < 2; ++kk) {
      const int lo = loff0 ^ (kk * 32);
      short8 bf[4], af[4], ag[4];
#pragma unroll
      for (int ni = 0; ni < 4; ++ni)
        bf[ni] = *(const short8*)(Bs + (wn * 64 + ni * 16) * 64 + lo);
#pragma unroll
      for (int mi = 0; mi < 4; ++mi)
        af[mi] = *(const short8*)(As + (aRowB + mi * 16) * 64 + lo);
#pragma unroll
      for (int mi = 0; mi < 4; ++mi)
        ag[mi] = *(const short8*)(As + (aRowB + 64 + mi * 16) * 64 + lo);
      __builtin_amdgcn_s_setprio(1);
#pragma unroll
      for (int mi = 0; mi < 4; ++mi)
#pragma unroll
        for (int ni = 0; ni < 4; ++ni)
          acc[mi][ni] = __builtin_amdgcn_mfma_f32_16x16x32_bf16(af[mi], bf[ni], acc[mi][ni], 0, 0, 0);
#pragma unroll
      for (int mi = 0; mi < 4; ++mi)
#pragma unroll
        for (int ni = 0; ni < 4; ++ni)
          acc[4 + mi][ni] = __builtin_amdgcn_mfma_f32_16x16x32_bf16(ag[mi], bf[ni], acc[4 + mi][ni], 0, 0, 0);
      __builtin_amdgcn_s_setprio(0);
    }
  }

  if constexpr (EPI == 1) {          // bf16 partial store
    unsigned short* C = p.C + (long)bz * p.sCb;
#pragma unroll
    for (int mi = 0; mi < 8; ++mi) {
#pragma unroll
      for (int ni = 0; ni < 4; ++ni) {
        const int col = n0 + wn * 64 + ni * 16 + l16;
#pragma unroll
        for (int r4 = 0; r4 < 4; ++r4) {
          const int row = m0 + wm * 128 + mi * 16 + g * 4 + r4;
          C[(long)row * p.ldc + col] = f2b(acc[mi][ni][r4]);
        }
      }
    }
  } else {
    // ------- staged epilogue: acc (+bias/scale for EPI2/3) -> LDS tile -------
    __syncthreads();
    char* shb = (char*)LDS;
    const int sel = (EPI == 2) ? (m0 >> 10) : (m0 >> 8);
#pragma unroll
    for (int mi = 0; mi < 8; ++mi) {
#pragma unroll
      for (int ni = 0; ni < 4; ++ni) {
        const int c = wn * 64 + ni * 16 + l16;
#pragma unroll
        for (int r4 = 0; r4 < 4; ++r4) {
          const int rr = wm * 128 + mi * 16 + g * 4 + r4;
          float v = acc[mi][ni][r4];
          if constexpr (EPI == 2 || EPI == 3) {
            v += p.bias[m0 + rr];
            if (sel == 0) {
              float sc;
              if constexpr (EPI == 2) sc = ((m0 & 1023) < 512) ? 0.011048543456039806f
                                                               : 0.02209708691207961f;
              else                    sc = (rr < 128) ? 0.011048543456039806f
                                                      : 0.02209708691207961f;
              v *= sc;
            }
          }
          *(unsigned short*)(shb + swz(rr, c * 2)) = f2b(v);
        }
      }
    }
    __syncthreads();

    if constexpr (EPI == 0) {
      unsigned short* C = p.C + (long)bz * p.sCb;
#pragma unroll
      for (int j = 0; j < 16; ++j) {
        const int e = j * 512 + tid;
        const int r = e >> 5, ck = e & 31;
        short8 v = *(const short8*)(shb + swz(r, ck * 16));
        *(short8*)(C + (long)(m0 + r) * p.ldc + n0 + ck * 8) = v;
      }
    } else if constexpr (EPI == 2) {    // ---- QKV lo ----
      const int chb = m0 & 1023;
      const bool cfg0 = chb < 512;
      const int b = bz >> 2, tt = bz & 3;
      const int k0 = n0 >> 8;
      unsigned short* dst = cfg0 ? (sel == 0 ? p.Q0 : sel == 1 ? p.K0 : p.V0t)
                                 : (sel == 0 ? p.Q1 : sel == 1 ? p.K1 : p.V1t);
      if (sel != 2) {
        if (cfg0) {                      // 4x4 patches, d=8192
          const long base = (long)(b * 512) * 8192;
#pragma unroll
          for (int j = 0; j < 16; ++j) {
            const int e = j * 512 + tid;
            const int pi = e >> 9, idx2 = e & 511;
            const int ch = idx2 >> 1, hf = idx2 & 1;
            const int oyL = pi >> 3, ox = pi & 7;
            const int nseq = (tt * 8 + 2 * k0 + oyL) * 8 + ox;
            const int yl = oyL * 4 + hf * 2;
            short4v a = *(const short4v*)(shb + swz(ch, (yl * 32 + ox * 4) * 2));
            short4v b2 = *(const short4v*)(shb + swz(ch, ((yl + 1) * 32 + ox * 4) * 2));
            short8 v = {a[0], a[1], a[2], a[3], b2[0], b2[1], b2[2], b2[3]};
            *(short8*)(dst + base + (long)nseq * 8192 + (chb + ch) * 16 + hf * 8) = v;
          }
        } else {                         // 2x2 patches, d=2048
          const int c2lo = chb - 512;
          const long base = (long)(b * 2048) * 2048;
#pragma unroll
          for (int j = 0; j < 16; ++j) {
            const int e = j * 512 + tid;
            const int pi = e >> 7, cp = e & 127;
            const int oyL = pi >> 4, ox = pi & 15;
            const int nseq = (tt * 16 + 4 * k0 + oyL) * 16 + ox;
            short8 v;
#pragma unroll
            for (int rr = 0; rr < 2; ++rr) {
#pragma unroll
              for (int k = 0; k < 2; ++k) {
                short2v pr = *(const short2v*)(shb +
                    swz(cp * 2 + rr, ((oyL * 2 + k) * 32 + ox * 2) * 2));
                v[rr * 4 + k * 2] = pr[0];
                v[rr * 4 + k * 2 + 1] = pr[1];
              }
            }
            *(short8*)(dst + base + (long)nseq * 2048 + (c2lo + cp * 2) * 4) = v;
          }
        }
      } else {                           // V transposed [f][nseq]
        if (cfg0) {
          const long base = (long)(b * 8192) * 512;
#pragma unroll
          for (int j = 0; j < 16; ++j) {
            const int e = j * 512 + tid;
            const int oyL = e >> 12, fu = e & 4095;
            const int ch = fu >> 4, pp = fu & 15;
            const int py = pp >> 2, px = pp & 3;
            const int yl = oyL * 4 + py;
            short8 v;
#pragma unroll
            for (int ox = 0; ox < 8; ++ox)
              v[ox] = *(const unsigned short*)(shb + swz(ch, (yl * 32 + ox * 4 + px) * 2));
            const long f = (long)(chb + ch) * 16 + pp;
            *(short8*)(dst + base + f * 512 + (tt * 8 + 2 * k0 + oyL) * 8) = v;
          }
        } else {
          const int c2lo = chb - 512;
          const long base = (long)(b * 2048) * 2048;
#pragma unroll
          for (int j = 0; j < 16; ++j) {
            const int e = j * 512 + tid;
            const int he = e & 1, oyL = (e >> 1) & 3, fu = e >> 3;
            const int c2 = fu >> 2, pp = fu & 3;
            const int py = pp >> 1, px = pp & 1;
            const int yl = oyL * 2 + py;
            short8 v;
#pragma unroll
            for (int i = 0; i < 8; ++i) {
              const int ox = he * 8 + i;
              v[i] = *(const unsigned short*)(shb + swz(c2, (yl * 32 + ox * 2 + px) * 2));
            }
            const long f = (long)(c2lo + c2) * 4 + pp;
            *(short8*)(dst + base + f * 2048 + (tt * 16 + 4 * k0 + oyL) * 16 + he * 8) = v;
          }
        }
      }
    } else if constexpr (EPI == 3) {    // ---- QKV hi ----
      const int b = bz >> 2, tt = bz & 3;
      const int k0 = n0 >> 8;
      const int oyA = k0 >> 1, pyb = (k0 & 1) * 4;
      unsigned short* dstA = sel == 0 ? p.Q0 : sel == 1 ? p.K0 : p.V0t;
      unsigned short* dstB = sel == 0 ? p.Q1 : sel == 1 ? p.K1 : p.V1t;
      if (sel != 2) {
#pragma unroll
        for (int j = 0; j < 16; ++j) {
          const int e = j * 512 + tid;
          if (e < 4096) {                // cfg0: 8x8 patches
            const int ox = e >> 9, cy = e & 511;
            const int ch = cy >> 2, yl = cy & 3;
            const int nseq = 256 + (tt * 8 + oyA) * 8 + ox;
            short8 v = *(const short8*)(shb + swz(ch, (yl * 64 + ox * 8) * 2));
            *(short8*)(dstA + ((long)(b * 512 + nseq)) * 8192 + ch * 64 + (pyb + yl) * 8) = v;
          } else {                       // cfg1: 4x4 patches
            const int ee = e - 4096;
            const int ox = ee >> 8, cc = ee & 255;
            const int c2 = cc >> 1, hf = cc & 1;
            const int nseq = 1024 + (tt * 16 + k0) * 16 + ox;
            short8 v;
#pragma unroll
            for (int k = 0; k < 2; ++k) {
              short4v a = *(const short4v*)(shb +
                  swz(128 + c2, ((hf * 2 + k) * 64 + ox * 4) * 2));
              v[k * 4] = a[0]; v[k * 4 + 1] = a[1]; v[k * 4 + 2] = a[2]; v[k * 4 + 3] = a[3];
            }
            *(short8*)(dstB + ((long)(b * 2048 + nseq)) * 2048 + c2 * 16 + hf * 8) = v;
          }
        }
      } else {
#pragma unroll
        for (int j = 0; j < 16; ++j) {
          const int e = j * 512 + tid;
          if (e < 4096) {                // cfg0 V
            const int ch = e >> 5, yl = (e >> 3) & 3, px = e & 7;
            short8 v;
#pragma unroll
            for (int ox = 0; ox < 8; ++ox)
              v[ox] = *(const unsigned short*)(shb + swz(ch, (yl * 64 + ox * 8 + px) * 2));
            const long f = (long)ch * 64 + (pyb + yl) * 8 + px;
            *(short8*)(dstA + ((long)b * 8192 + f) * 512 + 256 + (tt * 8 + oyA) * 8) = v;
          } else {                       // cfg1 V
            const int ee = e - 4096;
            const int he = ee & 1, fu = ee >> 1;
            const int c2 = fu >> 4, pp = fu & 15;
            const int py = pp >> 2, px = pp & 3;
            short8 v;
#pragma unroll
            for (int i = 0; i < 8; ++i) {
              const int x = (he * 8 + i) * 4 + px;
              v[i] = *(const unsigned short*)(shb + swz(128 + c2, (py * 64 + x) * 2));
            }
            const long f = (long)c2 * 16 + pp;
            *(short8*)(dstB + ((long)b * 2048 + f) * 2048 + 1024 + (tt * 16 + k0) * 16 + he * 8) = v;
          }
        }
      }
    } else if constexpr (EPI == 4) {    // ---- PV0 tile -> padded NHWC (cfg0) ----
      const int b = bz;
      if (m0 == 0) {                     // lo rows: 4x4 patches, CinLo ch 0..511
        const int chbase = n0 >> 4;
        unsigned short* dst = p.Q0;      // CinP_lo
#pragma unroll
        for (int j = 0; j < 16; ++j) {
          const int e = j * 512 + tid;
          const int hf = e & 1, pp = (e >> 1) & 15, rr = e >> 5;
          const int t = rr >> 6, oh = (rr >> 3) & 7, ow = rr & 7;
          const int bt = b * 4 + t;
          const int py = pp >> 2, px = pp & 3;
          short8 v;
#pragma unroll
          for (int i = 0; i < 8; ++i)
            v[i] = *(const unsigned short*)(shb + swz(rr, ((hf * 8 + i) * 16 + pp) * 2));
          *(short8*)(dst + (((long)bt * 34 + oh * 4 + py + 1) * 34 + ow * 4 + px + 1) * 1024
                     + chbase + hf * 8) = v;
        }
      } else {                           // hi rows: 8x8 patches, CinHi ch 0..127
        const int chbase = n0 >> 6;
        unsigned short* dst = p.Q1;      // CinP_hi
#pragma unroll
        for (int j = 0; j < 32; ++j) {
          const int e = j * 512 + tid;
          const int pp = e & 63, rr = e >> 6;
          const int t = rr >> 6, oh = (rr >> 3) & 7, ow = rr & 7;
          const int bt = b * 4 + t;
          const int py = pp >> 3, px = pp & 7;
          short4v v;
#pragma unroll
          for (int i = 0; i < 4; ++i)
            v[i] = *(const unsigned short*)(shb + swz(rr, (i * 64 + pp) * 2));
          *(short4v*)(dst + (((long)bt * 66 + oh * 8 + py + 1) * 66 + ow * 8 + px + 1) * 256
                      + chbase) = v;
        }
      }
    } else if constexpr (EPI == 5) {    // ---- PV1 tile -> padded NHWC (cfg1) ----
      const int b = bz;
      if (m0 < 1024) {                   // lo: 2x2 patches, CinLo ch 512..1023
        const int chbase = n0 >> 2;
        unsigned short* dst = p.Q0;
#pragma unroll
        for (int j = 0; j < 16; ++j) {
          const int e = j * 512 + tid;
          const int ch8 = e & 7, pp = (e >> 3) & 3, rr = e >> 5;
          const int n = m0 + rr;
          const int t = n >> 8, oh = (n >> 4) & 15, ow = n & 15;
          const int bt = b * 4 + t;
          const int py = pp >> 1, px = pp & 1;
          short8 v;
#pragma unroll
          for (int i = 0; i < 8; ++i)
            v[i] = *(const unsigned short*)(shb + swz(rr, ((ch8 * 8 + i) * 4 + pp) * 2));
          *(short8*)(dst + (((long)bt * 34 + oh * 2 + py + 1) * 34 + ow * 2 + px + 1) * 1024
                     + 512 + chbase + ch8 * 8) = v;
        }
      } else {                           // hi: 4x4 patches, CinHi ch 128..255
        const int chbase = n0 >> 4;
        unsigned short* dst = p.Q1;
#pragma unroll
        for (int j = 0; j < 16; ++j) {
          const int e = j * 512 + tid;
          const int hf = e & 1, pp = (e >> 1) & 15, rr = e >> 5;
          const int m = m0 + rr - 1024;
          const int t = m >> 8, oh = (m >> 4) & 15, ow = m & 15;
          const int bt = b * 4 + t;
          const int py = pp >> 2, px = pp & 3;
          short8 v;
#pragma unroll
          for (int i = 0; i < 8; ++i)
            v[i] = *(const unsigned short*)(shb + swz(rr, ((hf * 8 + i) * 16 + pp) * 2));
          *(short8*)(dst + (((long)bt * 66 + oh * 4 + py + 1) * 66 + ow * 4 + px + 1) * 256
                     + 128 + chbase + hf * 8) = v;
        }
      }
    }
  }
}

// ---------------------------------------------------------------------------
// 3x3 conv as im2col GEMM (same BK=64 2-buffer core). PARTIAL: bf16 slabs.
// ---------------------------------------------------------------------------
template<int H, int W, int CIN, int KS, bool PARTIAL>
__global__ __launch_bounds__(512) void conv256(const unsigned short* __restrict__ Cinp,
                                               const unsigned short* __restrict__ Wt,
                                               const float* __restrict__ bias,
                                               float* __restrict__ out,
                                               unsigned short* __restrict__ P0,
                                               unsigned short* __restrict__ P1) {
  constexpr int HP = H + 2, WP = W + 2;
  constexpr int CC = CIN / KS;
  constexpr int NT = 9 * CC / 64;
  __shared__ __align__(16) unsigned short LDS[65536];
  const int tid = threadIdx.x;
  const int wv = tid >> 6, lane = tid & 63;
  const int wm = wv >> 2, wn = wv & 3;
  const int g = lane >> 4, l16 = lane & 15;
  int bx = blockIdx.x, by = blockIdx.y, bz = blockIdx.z;
  xcd_remap(bx, by, bz);
  const int bt = bz / KS, ks = bz % KS;
  const int n0 = bx * 256;

  const int r0 = tid >> 3;
  const int cs8 = (tid & 7) ^ (r0 & 7);
  const unsigned short* wA[4];
  const unsigned short* pB[4];
#pragma unroll
  for (int i = 0; i < 4; ++i)
    wA[i] = Wt + (long)(r0 + 64 * i) * CIN + ks * CC + cs8 * 8;
  const unsigned short* cB = Cinp + (long)bt * HP * WP * CIN + ks * CC + cs8 * 8;
#pragma unroll
  for (int i = 0; i < 4; ++i) {
    const int pp = n0 + r0 + 64 * i;
    pB[i] = cB + ((long)(pp / W) * WP + (pp % W)) * CIN;
  }
  unsigned short* const lds0 = (unsigned short*)LDS;
  const int wbase = wv * 512;

  auto STAGE = [&](int t) {
    unsigned short* d = lds0 + (t & 1) * 32768;
    const int tap = t >> 2, tc = (t & 3) * 64;
    const long offA = (long)tap * (256L * CIN) + tc;
    const int ky = tap / 3, kx = tap - ky * 3;
    const long offB = ((long)ky * WP + kx) * CIN + tc;
#pragma unroll
    for (int i = 0; i < 4; ++i) glds16(wA[i] + offA, d + i * 4096 + wbase);
#pragma unroll
    for (int i = 0; i < 4; ++i) glds16(pB[i] + offB, d + 16384 + i * 4096 + wbase);
  };

  STAGE(0);

  floatx4 acc[8][4];
  const floatx4 z4 = {0.f, 0.f, 0.f, 0.f};
#pragma unroll
  for (int i = 0; i < 8; ++i)
#pragma unroll
    for (int j = 0; j < 4; ++j) acc[i][j] = z4;

  const int lmask = l16 & 7;
  const int loff0 = l16 * 64 + ((g ^ lmask) * 8);
  const int aRowB = wm * 128;

  for (int t = 0; t < NT; ++t) {
    const unsigned short* As = lds0 + (t & 1) * 32768;
    const unsigned short* Bs = As + 16384;
    asm volatile("s_waitcnt vmcnt(0)" ::: "memory");
    __builtin_amdgcn_s_barrier();
    __builtin_amdgcn_sched_barrier(0);
    if (t + 1 < NT) STAGE(t + 1);
#pragma unroll
    for (int kk = 0; kk < 2; ++kk) {
      const int lo = loff0 ^ (kk * 32);
      short8 bf[4], af[4], ag[4];
#pragma unroll
      for (int ni = 0; ni < 4; ++ni)
        bf[ni] = *(const short8*)(Bs + (wn * 64 + ni * 16) * 64 + lo);
#pragma unroll
      for (int mi = 0; mi < 4; ++mi)
        af[mi] = *(const short8*)(As + (aRowB + mi * 16) * 64 + lo);
#pragma unroll
      for (int mi = 0; mi < 4; ++mi)
        ag[mi] = *(const short8*)(As + (aRowB + 64 + mi * 16) * 64 + lo);
      __builtin_amdgcn_s_setprio(1);
#pragma unroll
      for (int mi = 0; mi < 4; ++mi)
#pragma unroll
        for (int ni = 0; ni < 4; ++ni)
          acc[mi][ni] = __builtin_amdgcn_mfma_f32_16x16x32_bf16(af[mi], bf[ni], acc[mi][ni], 0, 0, 0);
#pragma unroll
      for (int mi = 0; mi < 4; ++mi)
#pragma unroll
        for (int ni = 0; ni < 4; ++ni)
          acc[4 + mi][ni] = __builtin_amdgcn_mfma_f32_16x16x32_bf16(ag[mi], bf[ni], acc[4 + mi][ni], 0, 0, 0);
      __builtin_amdgcn_s_setprio(0);
    }
  }

  if constexpr (!PARTIAL) {
#pragma unroll
    for (int mi = 0; mi < 8; ++mi) {
#pragma unroll
      for (int ni = 0; ni < 4; ++ni) {
        const int pn = n0 + wn * 64 + ni * 16 + l16;
        const int y = pn / W, x = pn % W;
#pragma unroll
        for (int r4 = 0; r4 < 4; ++r4) {
          const int co = wm * 128 + mi * 16 + g * 4 + r4;
          float v = acc[mi][ni][r4] + bias[co];
          v = v > 0.f ? v : 0.2f * v;
          out[(((long)bt * 256 + co) * H + y) * W + x] = v;
        }
      }
    }
  } else {
    unsigned short* pout = (ks < 2 ? P0 : P1) + (long)(ks & 1) * (16L * 256 * H * W);
#pragma unroll
    for (int mi = 0; mi < 8; ++mi) {
#pragma unroll
      for (int ni = 0; ni < 4; ++ni) {
        const int pn = n0 + wn * 64 + ni * 16 + l16;
        const int y = pn / W, x = pn % W;
#pragma unroll
        for (int r4 = 0; r4 < 4; ++r4) {
          const int co = wm * 128 + mi * 16 + g * 4 + r4;
          pout[(((long)bt * 256 + co) * H + y) * W + x] = f2b(acc[mi][ni][r4]);
        }
      }
    }
  }
}

// ---------------------------------------------------------------------------
// Row softmax in-place on bf16 rows of length L. One wave per row.
// ---------------------------------------------------------------------------
template<int L>
__global__ __launch_bounds__(256) void softmax_rows(unsigned short* S) {
  const int w = threadIdx.x >> 6, lane = threadIdx.x & 63;
  const long row = (long)blockIdx.x * 4 + w;
  unsigned short* R = S + row * L;
  constexpr int NC = L / 64;
  float v[NC];
  float m = -1e30f;
#pragma unroll
  for (int i = 0; i < NC; ++i) { v[i] = b2f(R[i * 64 + lane]); m = fmaxf(m, v[i]); }
#pragma unroll
  for (int off = 32; off; off >>= 1) m = fmaxf(m, __shfl_xor(m, off, 64));
  float s = 0.f;
#pragma unroll
  for (int i = 0; i < NC; ++i) { v[i] = __expf(v[i] - m); s += v[i]; }
#pragma unroll
  for (int off = 32; off; off >>= 1) s += __shfl_xor(s, off, 64);
  const float inv = 1.0f / s;
#pragma unroll
  for (int i = 0; i < NC; ++i) R[i * 64 + lane] = f2b(v[i] * inv);
}

// ---------------------------------------------------------------------------
// S0: sum 16 bf16 split-K slabs [b*16+ks][512][512] -> softmax -> bf16
// ---------------------------------------------------------------------------
__global__ __launch_bounds__(256) void softmax_red16(const unsigned short* __restrict__ P,
                                                     unsigned short* __restrict__ S) {
  const int w = threadIdx.x >> 6, lane = threadIdx.x & 63;
  const int rowg = blockIdx.x * 4 + w;
  const int b = rowg >> 9, n = rowg & 511;
  const unsigned short* base = P + ((long)b * 16) * 262144 + (long)n * 512 + lane;
  float v[8];
#pragma unroll
  for (int i = 0; i < 8; ++i) {
    float s = 0.f;
#pragma unroll
    for (int ks = 0; ks < 16; ++ks) s += b2f(base[(long)ks * 262144 + i * 64]);
    v[i] = s;
  }
  float m = -1e30f;
#pragma unroll
  for (int i = 0; i < 8; ++i) m = fmaxf(m, v[i]);
#pragma unroll
  for (int off = 32; off; off >>= 1) m = fmaxf(m, __shfl_xor(m, off, 64));
  float s = 0.f;
#pragma unroll
  for (int i = 0; i < 8; ++i) { v[i] = __expf(v[i] - m); s += v[i]; }
#pragma unroll
  for (int off = 32; off; off >>= 1) s += __shfl_xor(s, off, 64);
  const float inv = 1.0f / s;
  unsigned short* R = S + (long)rowg * 512;
#pragma unroll
  for (int i = 0; i < 8; ++i) R[i * 64 + lane] = f2b(v[i] * inv);
}

// ---------------------------------------------------------------------------
// Combined x_lo/x_hi NCHW fp32 -> pixel-major bf16 transpose (1 dispatch).
// ---------------------------------------------------------------------------
__global__ __launch_bounds__(256) void xt_both(const float* __restrict__ x_lo,
                                               unsigned short* __restrict__ xt_lo,
                                               const float* __restrict__ x_hi,
                                               unsigned short* __restrict__ xt_hi) {
  __shared__ unsigned short tile[64 * 65];
  const int tid = threadIdx.x;
  const int blk = blockIdx.x;
  const float* x; unsigned short* xt; int NPIX, bxx, byy, bzz;
  if (blk < 1024) {
    x = x_lo; xt = xt_lo; NPIX = 1024;
    bxx = blk & 15; byy = (blk >> 4) & 3; bzz = blk >> 6;
  } else {
    const int q = blk - 1024;
    x = x_hi; xt = xt_hi; NPIX = 4096;
    bxx = q & 63; byy = (q >> 6) & 3; bzz = q >> 8;
  }
  const int ch0 = byy * 64;
  const long pix0 = (long)bxx * 64;
  const float* src = x + ((long)bzz * 256 + ch0) * NPIX + pix0;
#pragma unroll
  for (int i = 0; i < 16; ++i) {
    const int lin = i * 256 + tid;
    const int ch = lin >> 6, px = lin & 63;
    tile[ch * 65 + px] = f2b(src[(long)ch * NPIX + px]);
  }
  __syncthreads();
  unsigned short* dst = xt + ((long)bzz * NPIX + pix0) * 256 + ch0;
#pragma unroll
  for (int i = 0; i < 16; ++i) {
    const int lin = i * 256 + tid;
    const int px = lin >> 6, ch = lin & 63;
    dst[(long)px * 256 + ch] = tile[ch * 65 + px];
  }
}

// ---------------------------------------------------------------------------
// Combined QKV weight prep (lo 3072 blocks + hi 768 blocks, 1 dispatch).
// ---------------------------------------------------------------------------
__global__ void prep_qkv_both(const float* wq_lo, const float* wk_lo, const float* wv_lo,
                              const float* bq_lo, const float* bk_lo, const float* bv_lo,
                              unsigned short* Wcat_lo, float* Bcat_lo,
                              const float* wq_hi, const float* wk_hi, const float* wv_hi,
                              const float* bq_hi, const float* bk_hi, const float* bv_hi,
                              unsigned short* Wcat_hi, float* Bcat_hi) {
  const int blk = blockIdx.x;
  const float *wq, *wk, *wv, *bq, *bk, *bv;
  unsigned short* Wcat; float* Bcat; int CO, idx;
  if (blk < 3072) {
    wq = wq_lo; wk = wk_lo; wv = wv_lo; bq = bq_lo; bk = bk_lo; bv = bv_lo;
    Wcat = Wcat_lo; Bcat = Bcat_lo; CO = 1024;
    idx = blk * 256 + threadIdx.x;
  } else {
    wq = wq_hi; wk = wk_hi; wv = wv_hi; bq = bq_hi; bk = bk_hi; bv = bv_hi;
    Wcat = Wcat_hi; Bcat = Bcat_hi; CO = 256;
    idx = (blk - 3072) * 256 + threadIdx.x;
  }
  const int n = 3 * CO * 256;
  if (idx < n) {
    const int sel = idx / (CO * 256);
    const int r = idx - sel * CO * 256;
    const float* wsel = sel == 0 ? wq : (sel == 1 ? wk : wv);
    Wcat[idx] = f2b(wsel[r]);
  }
  if (idx < 3 * CO) {
    const int sel = idx / CO;
    const int r = idx - sel * CO;
    const float* bsel = sel == 0 ? bq : (sel == 1 ? bk : bv);
    Bcat[idx] = bsel[r];
  }
}

// ---------------------------------------------------------------------------
// Combined conv weight prep: wo [256][CIN][9] fp32 -> Wt [9][256][CIN] bf16.
// ---------------------------------------------------------------------------
__global__ __launch_bounds__(256) void prep_conv_both(const float* __restrict__ wo_lo,
                                                      unsigned short* __restrict__ Wt_lo,
                                                      const float* __restrict__ wo_hi,
                                                      unsigned short* __restrict__ Wt_hi) {
  __shared__ unsigned short T[9216];
  const int blk = blockIdx.x;
  const int tid = threadIdx.x;
  if (blk < 256) {                 // lo: OC=1, CIN=1024
    const int o0 = blk;
    const float* src = wo_lo + (long)o0 * 1024 * 9;
    for (int j = tid; j < 9216; j += 256) {
      const int t9 = j % 9, r = j / 9;
      T[t9 * 1024 + r] = f2b(src[j]);
    }
    __syncthreads();
#pragma unroll
    for (int t9 = 0; t9 < 9; ++t9)
      for (int j = tid; j < 1024; j += 256)
        Wt_lo[((long)t9 * 256 + o0) * 1024 + j] = T[t9 * 1024 + j];
  } else {                         // hi: OC=4, CIN=256
    const int o0 = (blk - 256) * 4;
    const float* src = wo_hi + (long)o0 * 256 * 9;
    for (int j = tid; j < 9216; j += 256) {
      const int t9 = j % 9, r = j / 9;
      T[t9 * 1024 + r] = f2b(src[j]);
    }
    __syncthreads();
#pragma unroll
    for (int t9 = 0; t9 < 9; ++t9)
      for (int j = tid; j < 1024; j += 256) {
        const int oo = j >> 8, i = j & 255;
        Wt_hi[((long)t9 * 256 + o0 + oo) * 256 + i] = T[t9 * 1024 + j];
      }
  }
}

// ---------------------------------------------------------------------------
// Combined halo-border zeroing for both padded NHWC buffers (1 dispatch).
// ---------------------------------------------------------------------------
__global__ __launch_bounds__(256) void zero_both(unsigned short* lo, unsigned short* hi) {
  const int blk = blockIdx.x;
  unsigned short* buf; int HP, WP, C; long i;
  if (blk < 1056) { buf = lo; HP = 34; WP = 34; C = 1024; i = (long)blk * 256 + threadIdx.x; }
  else            { buf = hi; HP = 66; WP = 66; C = 256;  i = (long)(blk - 1056) * 256 + threadIdx.x; }
  const int per_px = C >> 3;
  const int strip = 2 * WP + 2 * (HP - 2);
  const long tot = (long)16 * strip * per_px;
  if (i >= tot) return;
  const int c8 = (int)(i % per_px);
  const long r = i / per_px;
  const int s = (int)(r % strip);
  const int bt = (int)(r / strip);
  int y, x;
  if (s < WP) { y = 0; x = s; }
  else if (s < 2 * WP) { y = HP - 1; x = s - WP; }
  else if (s < 2 * WP + (HP - 2)) { y = s - 2 * WP + 1; x = 0; }
  else { y = s - 2 * WP - (HP - 2) + 1; x = WP - 1; }
  const short8 z = {0, 0, 0, 0, 0, 0, 0, 0};
  *(short8*)(buf + (((long)bt * HP + y) * WP + x) * C + c8 * 8) = z;
}

// ---------------------------------------------------------------------------
// Sum 4 bf16 conv partial slabs (2 in P0, 2 in P1) + bias + leaky-relu -> out
// ---------------------------------------------------------------------------
__global__ __launch_bounds__(256) void reduce_lrelu(const unsigned short* __restrict__ P0,
                                                    const unsigned short* __restrict__ P1,
                                                    const float* __restrict__ bias,
                                                    float* __restrict__ out) {
  const long i = (long)blockIdx.x * 256 + threadIdx.x;
  const long flat = i * 8;
  constexpr long SL = 4194304;
  short8 a = *(const short8*)(P0 + flat);
  short8 b = *(const short8*)(P0 + SL + flat);
  short8 c = *(const short8*)(P1 + flat);
  short8 d = *(const short8*)(P1 + SL + flat);
  const int co = ((int)(flat >> 10)) & 255;
  const float bv = bias[co];
  floatx4 r0, r1;
#pragma unroll
  for (int j = 0; j < 8; ++j) {
    float v = b2f((unsigned short)a[j]) + b2f((unsigned short)b[j]) +
              b2f((unsigned short)c[j]) + b2f((unsigned short)d[j]) + bv;
    v = v > 0.f ? v : 0.2f * v;
    if (j < 4) r0[j] = v; else r1[j - 4] = v;
  }
  *(floatx4*)(out + flat) = r0;
  *(floatx4*)(out + flat + 4) = r1;
}

// ---------------------------------------------------------------------------
extern "C" void kernel_launch(void* const* d_in, const int* in_sizes, int n_in,
                              void* d_out, int out_size, void* d_ws, size_t ws_size,
                              hipStream_t stream) {
  (void)in_sizes; (void)n_in; (void)out_size; (void)ws_size;
  const float* x_lo = (const float*)d_in[0];
  const float* x_hi = (const float*)d_in[1];
  const float* wq_lo = (const float*)d_in[3];
  const float* bq_lo = (const float*)d_in[4];
  const float* wk_lo = (const float*)d_in[5];
  const float* bk_lo = (const float*)d_in[6];
  const float* wv_lo = (const float*)d_in[7];
  const float* bv_lo = (const float*)d_in[8];
  const float* wq_hi = (const float*)d_in[9];
  const float* bq_hi = (const float*)d_in[10];
  const float* wk_hi = (const float*)d_in[11];
  const float* bk_hi = (const float*)d_in[12];
  const float* wv_hi = (const float*)d_in[13];
  const float* bv_hi = (const float*)d_in[14];
  const float* wo_lo = (const float*)d_in[15];
  const float* bo_lo = (const float*)d_in[16];
  const float* wo_hi = (const float*)d_in[17];
  const float* bo_hi = (const float*)d_in[18];
  float* out = (float*)d_out;

  char* ws = (char*)d_ws;
  const long B0 = 33554432;
  unsigned short* Qp0 = (unsigned short*)(ws);            // later: CinP_lo (+ Kp0 spill)
  unsigned short* Kp0 = (unsigned short*)(ws + B0);
  unsigned short* V0t = (unsigned short*)(ws + 2 * B0);   // later: conv partials PC0
  unsigned short* Qp1 = (unsigned short*)(ws + 3 * B0);   // later: CinP_hi (+ Kp1 spill)
  unsigned short* Kp1 = (unsigned short*)(ws + 4 * B0);
  unsigned short* V1t = (unsigned short*)(ws + 5 * B0);   // later: conv partials PC1
  char* ptr = ws + 6 * B0;
  unsigned short* S0 = (unsigned short*)ptr;     ptr += 2097152;
  unsigned short* Xt_lo = (unsigned short*)ptr;  ptr += 8388608;
  unsigned short* Xt_hi = (unsigned short*)ptr;  ptr += 33554432;   // later: S0p, then S1
  unsigned short* Wcat_lo = (unsigned short*)ptr; ptr += 1572864;
  unsigned short* Wcat_hi = (unsigned short*)ptr; ptr += 393216;
  float* Bcat_lo = (float*)ptr;                  ptr += 12288;
  float* Bcat_hi = (float*)ptr;                  ptr += 3072;
  unsigned short* Wt_lo = (unsigned short*)ptr;  ptr += 4718592;
  unsigned short* Wt_hi = (unsigned short*)ptr;  ptr += 1179648;
  unsigned short* S0p = Xt_hi;          // S0 bf16 partials (33.5 MB), dead after red16
  unsigned short* S1 = Xt_hi;           // S1 written after red16 consumed S0p
  unsigned short* CinP_lo = Qp0;        // 37.9 MB: Qp0 + spill into Kp0 (both dead)
  unsigned short* CinP_hi = Qp1;        // 35.7 MB: Qp1 + spill into Kp1 (both dead)
  unsigned short* PC0 = V0t;            // conv_lo bf16 partial slabs 0,1
  unsigned short* PC1 = V1t;            // slabs 2,3

  // --- fused weight/input prep (3 dispatches) ---
  prep_qkv_both<<<3840, 256, 0, stream>>>(
      wq_lo, wk_lo, wv_lo, bq_lo, bk_lo, bv_lo, Wcat_lo, Bcat_lo,
      wq_hi, wk_hi, wv_hi, bq_hi, bk_hi, bv_hi, Wcat_hi, Bcat_hi);
  prep_conv_both<<<320, 256, 0, stream>>>(wo_lo, Wt_lo, wo_hi, Wt_hi);
  xt_both<<<5120, 256, 0, stream>>>(x_lo, Xt_lo, x_hi, Xt_hi);

  // --- QKV projections (1x1 conv as TN-GEMM), staged coalesced scatter ---
  {
    GemmP p{};
    p.A = Wcat_lo; p.B = Xt_lo; p.sAb = 0; p.sBb = 1024L * 256;
    p.lda = 256; p.ldb = 256; p.K = 256;
    p.bias = Bcat_lo;
    p.Q0 = Qp0; p.K0 = Kp0; p.V0t = V0t; p.Q1 = Qp1; p.K1 = Kp1; p.V1t = V1t;
    gemm256<2><<<dim3(4, 12, 16), 512, 0, stream>>>(p);
    p.A = Wcat_hi; p.B = Xt_hi; p.sBb = 4096L * 256; p.bias = Bcat_hi;
    gemm256<3><<<dim3(16, 3, 16), 512, 0, stream>>>(p);
  }

  // --- S0 scores: n=512, d=8192 (split-K 16, bf16 partials) + softmax ---
  {
    GemmP s{};
    s.A = Qp0; s.B = Kp0; s.sAb = 512L * 8192; s.sBb = 512L * 8192;
    s.lda = 8192; s.ldb = 8192; s.K = 8192;
    s.C = S0p; s.sCb = 262144; s.ldc = 512;
    gemm256<1><<<dim3(2, 2, 64), 512, 0, stream>>>(s);
    softmax_red16<<<512, 256, 0, stream>>>(S0p, S0);
  }

  // --- S1 scores: n=2048, d=2048 (into Xt_hi region) + softmax ---
  {
    GemmP s{};
    s.A = Qp1; s.B = Kp1; s.sAb = 2048L * 2048; s.sBb = 2048L * 2048;
    s.lda = 2048; s.ldb = 2048; s.K = 2048;
    s.C = S1; s.sCb = 2048L * 2048; s.ldc = 2048;
    gemm256<0><<<dim3(8, 8, 4), 512, 0, stream>>>(s);
    softmax_rows<2048><<<2048, 256, 0, stream>>>(S1);
  }

  // --- halo zeroing, then PV with fused repack ---
  zero_both<<<1576, 256, 0, stream>>>(CinP_lo, CinP_hi);
  {
    GemmP pv{};
    pv.A = S0; pv.B = V0t; pv.sAb = 512L * 512; pv.sBb = 8192L * 512;
    pv.lda = 512; pv.ldb = 512; pv.K = 512;
    pv.Q0 = CinP_lo; pv.Q1 = CinP_hi;
    gemm256<4><<<dim3(32, 2, 4), 512, 0, stream>>>(pv);
  }
  {
    GemmP pv{};
    pv.A = S1; pv.B = V1t; pv.sAb = 2048L * 2048; pv.sBb = 2048L * 2048;
    pv.lda = 2048; pv.ldb = 2048; pv.K = 2048;
    pv.Q0 = CinP_lo; pv.Q1 = CinP_hi;
    gemm256<5><<<dim3(8, 8, 4), 512, 0, stream>>>(pv);
  }

  // --- 3x3 convs as im2col GEMM on the BK=64 pipeline ---
  conv256<32, 32, 1024, 4, true><<<dim3(4, 1, 64), 512, 0, stream>>>(
      CinP_lo, Wt_lo, bo_lo, out, PC0, PC1);
  reduce_lrelu<<<2048, 256, 0, stream>>>(PC0, PC1, bo_lo, out);
  conv256<64, 64, 256, 1, false><<<dim3(16, 1, 16), 512, 0, stream>>>(
      CinP_hi, Wt_hi, bo_hi, out + 4194304, nullptr, nullptr);
}